// Round 8
// baseline (17472.444 us; speedup 1.0000x reference)
//
#include <hip/hip_runtime.h>
#include <cstddef>
#include <math.h>

#define SEQ   256
#define BATCH 2048
#define FD    5
#define HD    64
#define ROWS  4
#define NTHR  256
#define NBLK  (BATCH / ROWS)       // 512 blocks -> 2 blocks/CU
#define STEP_STRIDE (BATCH * FD)

// workspace layout (floats)
#define UT_F   (1600 * 64)         // UtE2: unified recurrent cols
#define WFB_F  (5 * 256 * 8)       // input-proj weights + bias per regular col
#define IHT_F  (16 * 4 * 64 * 4)   // W_ih transposed [hb][q][lane] float4

// libm activations (~1-2 ulp): fast __expf variants amplified to 8e-3 over 256 steps.
__device__ __forceinline__ float sigm(float x) { return 1.0f / (1.0f + expf(-x)); }

__device__ __forceinline__ float wave_sum(float v) {
#pragma unroll
    for (int m = 1; m < 64; m <<= 1) v += __shfl_xor(v, m);
    return v;
}
__device__ __forceinline__ float fma4(float4 w, float4 h, float a) {
    return fmaf(w.x, h.x, fmaf(w.y, h.y, fmaf(w.z, h.z, fmaf(w.w, h.w, a))));
}

// Unified column table UtE2[c][h] (contiguous per column):
//  c in [0,256):     U_main[:,c]            (state h1)
//  c in [256,1280):  U_aux[kk][:,gg]        (state h1)
//  c in [1280,1344): W_att[c-1280,:]        (state c1)
//  c in [1344,1600): W_hh[c-1344,:]         (state h2)
__global__ void prep(const float* __restrict__ U_main, const float* __restrict__ U_aux,
                     const float* __restrict__ W_att,  const float* __restrict__ W_hh,
                     const float* __restrict__ W_ih,   const float* __restrict__ W_main,
                     const float* __restrict__ W_aux,  const float* __restrict__ b_main,
                     const float* __restrict__ b_aux,  float* __restrict__ ws) {
    const int b = blockIdx.x, ln = threadIdx.x;
    float* UtE2 = ws;
    float* Wfb  = ws + UT_F;
    float* ihT  = ws + UT_F + WFB_F;
    if (b < 1600) {
        const int c = b;
        float v;
        if (c < 256)       v = U_main[ln * 256 + c];
        else if (c < 1280) { int cp = c - 256, kk = cp >> 7, gg = cp & 127;
                             v = U_aux[(size_t)kk * 64 * 128 + ln * 128 + gg]; }
        else if (c < 1344) v = W_att[(c - 1280) * 64 + ln];
        else               v = W_hh[(size_t)(c - 1344) * 64 + ln];
        UtE2[(size_t)c * 64 + ln] = v;
        if (ln < 8 && c < 1280) {
            float u = 0.0f;
            if (ln < 5) {
                if (c < 256) u = W_main[ln * 256 + c];
                else { int cp = c - 256, kk = cp >> 7, gg = cp & 127;
                       u = W_aux[(kk * 5 + ln) * 128 + gg]; }
            } else if (ln == 5) {
                if (c < 256) u = b_main[c];
                else { int cp = c - 256, kk = cp >> 7, gg = cp & 127;
                       u = b_aux[kk * 128 + gg]; }
            }
            Wfb[((size_t)(c >> 8) * 256 + (c & 255)) * 8 + ln] = u;
        }
    } else {
        const int bb = b - 1600;            // 0..63: hb = bb>>2, q = bb&3
        const int hb = bb >> 2, q = bb & 3;
        float4 v = *(const float4*)(W_ih + (size_t)(64 * q + ln) * 64 + 4 * hb);
        ((float4*)ihT)[(size_t)(hb * 4 + q) * 64 + ln] = v;
    }
}

// (256,2): 8 waves/CU target -> 256-VGPR cap (the (512,2) variant forced 128 and 56GB spills, r4)
__global__ __launch_bounds__(NTHR, 2)
void minet_fused(const float* __restrict__ Y,
                 const float* __restrict__ x1, const float* __restrict__ x2,
                 const float* __restrict__ x3, const float* __restrict__ x4,
                 const float* __restrict__ x5, const float* __restrict__ x6,
                 const float* __restrict__ x7, const float* __restrict__ x8,
                 const float* __restrict__ ws,
                 const float* __restrict__ b_ih, const float* __restrict__ b_hh,
                 const float* __restrict__ lin_W, const float* __restrict__ lin_b,
                 const float* __restrict__ b_att,
                 float* __restrict__ out)
{
    __shared__ __align__(16) float h1[ROWS][HD];
    __shared__ __align__(16) float c1s[ROWS][HD];
    __shared__ __align__(16) float h2[ROWS][HD];
    __shared__ __align__(16) float outb[ROWS][1344];   // 1280 regular + 64 att
    __shared__ __align__(16) float ghh[ROWS][256];     // LSTM2 hh-part
    __shared__ __align__(16) float inb[ROWS][72];      // 9 slots * 8

    const float*  UtE2 = ws;
    const float*  Wfb  = ws + UT_F;
    const float4* ihT  = (const float4*)(ws + UT_F + WFB_F);

    const int tid  = threadIdx.x;
    const int lane = tid & 63;
    const int wid  = tid >> 6;              // wave w owns batch row w in P5/P6ih/P7
    const int b0   = blockIdx.x * ROWS;

    // --- per-thread column ownership: 5 regular + 1 hh + (lanes<16) 1 att
    const float* up[5];
    float wf[5][5]; float bias[5]; int inoff[5];
#pragma unroll
    for (int j = 0; j < 5; ++j) {
        const int c = tid + 256 * j;
        up[j] = UtE2 + (size_t)c * 64;
        const float* wb = Wfb + ((size_t)j * 256 + tid) * 8;
#pragma unroll
        for (int f = 0; f < FD; ++f) wf[j][f] = wb[f];
        bias[j]  = wb[5];
        inoff[j] = (j == 0) ? 0 : (1 + ((c - 256) >> 7)) * 8;
    }
    const float* uph = UtE2 + (size_t)(1344 + tid) * 64;     // W_hh row tid
    const bool hasatt = (lane < 16);
    const int  attc   = wid * 16 + (lane & 15);
    const float* upa  = UtE2 + (size_t)(1280 + attc) * 64;   // W_att row attc

    float b2q[4];
#pragma unroll
    for (int q = 0; q < 4; ++q) b2q[q] = b_ih[64 * q + lane] + b_hh[64 * q + lane];
    const float linw = lin_W[lane];
    const float linb = lin_b[0];
    const float batt = b_att[0];

    // zero states
    for (int i = tid; i < ROWS * HD; i += NTHR) {
        (&h1[0][0])[i] = 0.f; (&c1s[0][0])[i] = 0.f; (&h2[0][0])[i] = 0.f;
    }
    for (int i = tid; i < ROWS * 72; i += NTHR) (&inb[0][0])[i] = 0.f;

    float c1reg = 0.f;   // MI-LSTM cell (row=wid, unit=lane)
    float c2reg = 0.f;   // LSTM2 cell

    // input prefetch: 180 = 4 rows x 9 slots x 5 feats (threads 0..179)
    const bool pon = (tid < 180);
    const float* psrc = Y;
    int pofs = 0; float pf = 0.f;
    if (pon) {
        int r = tid / 45, rem = tid % 45, s = rem / 5, f = rem % 5;
        const float* base = Y;
        if (s == 1) base = x1; else if (s == 2) base = x2; else if (s == 3) base = x3;
        else if (s == 4) base = x4; else if (s == 5) base = x5; else if (s == 6) base = x6;
        else if (s == 7) base = x7; else if (s == 8) base = x8;
        psrc = base + (size_t)(b0 + r) * FD + f;
        pofs = r * 72 + s * 8 + f;
        pf   = psrc[0];
    }

    for (int t = 0; t < SEQ; ++t) {
        if (pon) (&inb[0][0])[pofs] = pf;
        __syncthreads();                       // BAR_A: states(t-1) + inputs(t) visible
        if (pon && t + 1 < SEQ) pf = psrc[(size_t)(t + 1) * STEP_STRIDE];

        // ---- P3: unified 1600+att col stream vs {h1,h2,c1}(t-1)
        float acc[5][ROWS], acch[ROWS], acca[ROWS];
#pragma unroll
        for (int j = 0; j < 5; ++j)
#pragma unroll
            for (int r = 0; r < ROWS; ++r) {
                const float* ip = &inb[r][inoff[j]];
                float4 ia = *(const float4*)ip;
                float  i4 = ip[4];
                acc[j][r] = bias[j] + ia.x * wf[j][0] + ia.y * wf[j][1] + ia.z * wf[j][2]
                                    + ia.w * wf[j][3] + i4 * wf[j][4];
            }
#pragma unroll
        for (int r = 0; r < ROWS; ++r) { acch[r] = 0.f; acca[r] = 0.f; }

#pragma unroll 4
        for (int hb = 0; hb < 16; ++hb) {
            float4 w0 = *(const float4*)(up[0] + hb * 4);
            float4 w1 = *(const float4*)(up[1] + hb * 4);
            float4 w2 = *(const float4*)(up[2] + hb * 4);
            float4 w3 = *(const float4*)(up[3] + hb * 4);
            float4 w4 = *(const float4*)(up[4] + hb * 4);
            float4 wh = *(const float4*)(uph   + hb * 4);
            float4 wa;
            if (hasatt) wa = *(const float4*)(upa + hb * 4);
#pragma unroll
            for (int r = 0; r < ROWS; ++r) {
                float4 x = *(const float4*)&h1[r][hb * 4];   // lane-broadcast, conflict-free
                acc[0][r] = fma4(w0, x, acc[0][r]);
                acc[1][r] = fma4(w1, x, acc[1][r]);
                acc[2][r] = fma4(w2, x, acc[2][r]);
                acc[3][r] = fma4(w3, x, acc[3][r]);
                acc[4][r] = fma4(w4, x, acc[4][r]);
                float4 y = *(const float4*)&h2[r][hb * 4];
                acch[r] = fma4(wh, y, acch[r]);
                if (hasatt) {
                    float4 z = *(const float4*)&c1s[r][hb * 4];
                    acca[r] = fma4(wa, z, acca[r]);
                }
            }
        }
#pragma unroll
        for (int j = 0; j < 5; ++j)
#pragma unroll
            for (int r = 0; r < ROWS; ++r)
                outb[r][tid + 256 * j] = acc[j][r];
#pragma unroll
        for (int r = 0; r < ROWS; ++r) ghh[r][tid] = acch[r];
        if (hasatt)
#pragma unroll
            for (int r = 0; r < ROWS; ++r) outb[r][1280 + attc] = acca[r];
        __syncthreads();                       // BAR_B: outb + ghh ready

        // ---- P5: gates + attention softmax + MI state update (row = wid, wave-local)
        {
            const int r = wid;
            const float v0 = outb[r][1280 + lane];
            float gi = outb[r][lane],       gf = outb[r][64 + lane];
            float go = outb[r][128 + lane], gc = outb[r][192 + lane];
            float ii = sigm(gi), ff = sigm(gf), oo = sigm(go), cm = tanhf(gc);
            float l[9];
            l[0] = ii * cm;
#pragma unroll
            for (int k = 1; k <= 8; ++k) {
                float a_ = outb[r][256 + (k - 1) * 128 + lane];
                float b_ = outb[r][256 + (k - 1) * 128 + 64 + lane];
                l[k] = sigm(a_) * tanhf(b_);
            }
            float u[9]; float um = -1e30f;
#pragma unroll
            for (int k = 0; k < 9; ++k) {
                u[k] = tanhf(wave_sum(l[k] * v0) + batt);
                um = fmaxf(um, u[k]);
            }
            float den = 0.f, Lh = 0.f;
#pragma unroll
            for (int k = 0; k < 9; ++k) {
                float e = expf(u[k] - um); den += e; Lh = fmaf(e, l[k], Lh);
            }
            Lh /= den;
            float cn = fmaf(ff, c1reg, Lh); c1reg = cn;
            float hn = oo * tanhf(cn);
            h1[r][lane] = hn;                  // wave-local write; cross-wave read after next BAR_A
            c1s[r][lane] = cn;
        }

        // ---- P6ih: wave-local ih-projection for row wid (uses h1[wid] just written; same-wave
        //            LDS RAW — compiler orders via lgkmcnt, no barrier needed)
        float pre[4] = {b2q[0], b2q[1], b2q[2], b2q[3]};
#pragma unroll 4
        for (int hb = 0; hb < 16; ++hb) {
            float4 hv = *(const float4*)&h1[wid][hb * 4];
#pragma unroll
            for (int q = 0; q < 4; ++q) {
                float4 wi = ihT[(size_t)(hb * 4 + q) * 64 + lane];
                pre[q] = fma4(wi, hv, pre[q]);
            }
        }
#pragma unroll
        for (int q = 0; q < 4; ++q) pre[q] += ghh[wid][64 * q + lane];

        // ---- P7: LSTM2 gates (i,f,g,o) + projection
        {
            float i2 = sigm(pre[0]), f2 = sigm(pre[1]);
            float g2 = tanhf(pre[2]), o2 = sigm(pre[3]);
            c2reg = fmaf(f2, c2reg, i2 * g2);
            float hn2 = o2 * tanhf(c2reg);
            h2[wid][lane] = hn2;
            float e = wave_sum(fmaxf(hn2, 0.f) * linw);
            if (lane == 0) out[(size_t)t * BATCH + b0 + wid] = e + linb;
        }
        // next BAR_A separates these state writes from all cross-wave reads
    }
}

extern "C" void kernel_launch(void* const* d_in, const int* in_sizes, int n_in,
                              void* d_out, int out_size, void* d_ws, size_t ws_size,
                              hipStream_t stream) {
    const float* Y      = (const float*)d_in[0];
    const float* x1     = (const float*)d_in[1];
    const float* x2     = (const float*)d_in[2];
    const float* x3     = (const float*)d_in[3];
    const float* x4     = (const float*)d_in[4];
    const float* x5     = (const float*)d_in[5];
    const float* x6     = (const float*)d_in[6];
    const float* x7     = (const float*)d_in[7];
    const float* x8     = (const float*)d_in[8];
    const float* W_main = (const float*)d_in[9];
    const float* U_main = (const float*)d_in[10];
    const float* b_main = (const float*)d_in[11];
    const float* W_aux  = (const float*)d_in[12];
    const float* U_aux  = (const float*)d_in[13];
    const float* b_aux  = (const float*)d_in[14];
    const float* W_att  = (const float*)d_in[15];
    const float* b_att  = (const float*)d_in[16];
    const float* W_ih   = (const float*)d_in[17];
    const float* W_hh   = (const float*)d_in[18];
    const float* b_ih   = (const float*)d_in[19];
    const float* b_hh   = (const float*)d_in[20];
    const float* lin_W  = (const float*)d_in[21];
    const float* lin_b  = (const float*)d_in[22];
    float* out = (float*)d_out;
    float* ws  = (float*)d_ws;   // 516 KB

    prep<<<dim3(1664), dim3(HD), 0, stream>>>(U_main, U_aux, W_att, W_hh, W_ih,
                                              W_main, W_aux, b_main, b_aux, ws);

    dim3 grid(NBLK);    // 512 blocks -> 2 independent barrier groups per CU
    dim3 block(NTHR);
    minet_fused<<<grid, block, 0, stream>>>(Y, x1, x2, x3, x4, x5, x6, x7, x8,
                                            ws, b_ih, b_hh, lin_W, lin_b, b_att, out);
}